// Round 9
// baseline (217.722 us; speedup 1.0000x reference)
//
#include <hip/hip_runtime.h>

#define N_NODES 100000
#define N_EDGES 1600000
#define IN_F 128
#define H_F 64
#define C_F 16

#define BIN_SH 7
#define BIN_NODES 128          // 1 << BIN_SH
#define NBINS 782              // ceil(100000 / 128)
#define BCAP 2816              // per-bin total cap (mean 2048, sigma 45 -> +17s)
#define PART_BLOCKS 196        // ceil(400000 int4 / 2048) - 8192 edges/block
#define PBE 8192               // edges per partition block (region size)
#define GEMM1_BLOCKS 1563      // ceil(6250 row-tiles / 4 waves)
#define AGG_STRIDE 36          // LDS agg tile row stride in words (144 B)

typedef __attribute__((ext_vector_type(8))) short bf16x8;  // 8 bf16 (4 VGPRs)
typedef __attribute__((ext_vector_type(4))) float f32x4;   // MFMA C/D

// fp32 -> bf16 round-to-nearest-even (finite inputs)
__device__ inline unsigned short f2bf(float f) {
  unsigned u = __float_as_uint(f);
  unsigned r = (u + 0x7fff + ((u >> 16) & 1)) >> 16;
  return (unsigned short)r;
}

// ---------------- fused partition + GEMM1 (independent work) --------------
// Blocks [0, PART_BLOCKS): per-block-region partition. Block sorts its 8192
// edges by bin IN ITS OWN contiguous region (LDS hist -> 782-bin scan ->
// LDS-cursor scatter). All lines of the region are dirtied by ONE block/L2
// -> zero cross-XCD partial-line writeback (R4/R8 established that as K1's
// cost). No global atomics, no binCnt, no memset. Writes per-block offset
// table offT[blk][bin] (+ end sentinel) for the gather kernels.
// Record = 4 B (src | wf<<17) + 1 B dst-lane in a parallel byte array.
// Blocks [PART_BLOCKS..): MFMA GEMM1 H1b = bf16(X @ W1).
__global__ __launch_bounds__(256) void part_gemm1_kernel(
    const int* __restrict__ src, const int* __restrict__ dst,
    const float* __restrict__ ew, unsigned* __restrict__ rec4,
    unsigned char* __restrict__ dl1, int* __restrict__ offT,
    const float* __restrict__ X, const float* __restrict__ W1,
    unsigned short* __restrict__ H1b) {
  __shared__ char ldsraw[16 * 1024];
  int tid = threadIdx.x;
  if (blockIdx.x < PART_BLOCKS) {
    // ---- partition path ----
    int* hist = (int*)ldsraw;     // 784 ints (padded to 4*196)
    int* cur = hist + 784;        // 782 ints (within-block cursors)
    int* part = cur + 782;        // 196 ints (scan partials)
    for (int i = tid; i < 784; i += 256) hist[i] = 0;
    __syncthreads();
    int i0 = blockIdx.x * (PBE / 4);  // int4 index base
    int iHi = i0 + (PBE / 4);
    if (iHi > N_EDGES / 4) iHi = N_EDGES / 4;
    const int4* d4p = (const int4*)dst;
    const int4* s4p = (const int4*)src;
    const float4* w4p = (const float4*)ew;
    unsigned r4[32];
    int dd32[32];
#pragma unroll
    for (int it = 0; it < 8; ++it) {
      int i = i0 + it * 256 + tid;
      if (i < iHi) {
        int4 d = d4p[i];
        int4 s = s4p[i];
        float4 w = w4p[i];
#pragma unroll
        for (int j = 0; j < 4; ++j) {
          int dd = (&d.x)[j];
          int ss = (&s.x)[j];
          float ww = (&w.x)[j];
          unsigned wf = (unsigned)(ww * 32767.0f + 0.5f);
          r4[it * 4 + j] = (unsigned)ss | (wf << 17);
          dd32[it * 4 + j] = dd;
          atomicAdd(&hist[dd >> BIN_SH], 1);
        }
      }
    }
    __syncthreads();
    // exclusive scan over 782 bins: 4 bins/thread serial + 196-wide scan
    int sl1 = 0, sl2 = 0, sl3 = 0;
    if (tid < 196) {
      int b0 = tid * 4;
      int v0 = hist[b0], v1 = hist[b0 + 1], v2 = hist[b0 + 2],
          v3 = hist[b0 + 3];
      sl1 = v0;
      sl2 = v0 + v1;
      sl3 = v0 + v1 + v2;
      part[tid] = v0 + v1 + v2 + v3;
    }
    __syncthreads();
    for (int d = 1; d < 196; d <<= 1) {
      int t = 0;
      if (tid < 196 && tid >= d) t = part[tid - d];
      __syncthreads();
      if (tid < 196) part[tid] += t;
      __syncthreads();
    }
    int blkBase = blockIdx.x * PBE;
    if (tid < 196) {
      int base0 = tid ? part[tid - 1] : 0;
      int b0 = tid * 4;
      int* op = offT + blockIdx.x * 783;
      cur[b0] = base0;
      op[b0] = blkBase + base0;
      cur[b0 + 1] = base0 + sl1;
      op[b0 + 1] = blkBase + base0 + sl1;
      if (b0 + 2 < NBINS) {
        cur[b0 + 2] = base0 + sl2;
        op[b0 + 2] = blkBase + base0 + sl2;
        cur[b0 + 3] = base0 + sl3;
        op[b0 + 3] = blkBase + base0 + sl3;
      }
    }
    if (tid == 0)
      offT[blockIdx.x * 783 + 782] = blkBase + (iHi - i0) * 4;  // end sentinel
    __syncthreads();
    // scatter into own region (blkBase + within-block cursor)
#pragma unroll
    for (int it = 0; it < 8; ++it) {
      int i = i0 + it * 256 + tid;
      if (i < iHi) {
        int pos[4];
#pragma unroll
        for (int j = 0; j < 4; ++j)
          pos[j] = atomicAdd(&cur[dd32[it * 4 + j] >> BIN_SH], 1);
#pragma unroll
        for (int j = 0; j < 4; ++j) {
          int g = blkBase + pos[j];
          rec4[g] = r4[it * 4 + j];
          dl1[g] = (unsigned char)(dd32[it * 4 + j] & (BIN_NODES - 1));
        }
      }
    }
  } else {
    // ---- gemm1 path ----
    short* ldsB = (short*)ldsraw;  // 16 frags x 512 bf16 = 16 KB
    for (int idx = tid; idx < 16 * 512; idx += 256) {
      int frag = idx >> 9;    // c*4 + s
      int entry = idx & 511;  // lane*8 + j
      int lane = entry >> 3, j = entry & 7;
      int c = frag >> 2, s = frag & 3;
      int k = s * 32 + (lane >> 4) * 8 + j;
      int n = c * 16 + (lane & 15);
      ldsB[idx] = (short)f2bf(W1[k * H_F + n]);
    }
    __syncthreads();
    int wave = tid >> 6;
    int lane = tid & 63;
    int rt = (blockIdx.x - PART_BLOCKS) * 4 + wave;  // 16-node row tile
    if (rt >= N_NODES / 16) return;                  // 6250 tiles exactly
    int node0 = rt * 16;
    int l = lane & 15, q = lane >> 4;
    const float* xp = X + (size_t)(node0 + l) * IN_F + q * 8;
    f32x4 acc[4] = {f32x4{0.f, 0.f, 0.f, 0.f}, f32x4{0.f, 0.f, 0.f, 0.f},
                    f32x4{0.f, 0.f, 0.f, 0.f}, f32x4{0.f, 0.f, 0.f, 0.f}};
#pragma unroll
    for (int s = 0; s < 4; ++s) {
      float4 x0 = *(const float4*)(xp + s * 32);
      float4 x1 = *(const float4*)(xp + s * 32 + 4);
      bf16x8 a;
      a[0] = f2bf(x0.x); a[1] = f2bf(x0.y); a[2] = f2bf(x0.z); a[3] = f2bf(x0.w);
      a[4] = f2bf(x1.x); a[5] = f2bf(x1.y); a[6] = f2bf(x1.z); a[7] = f2bf(x1.w);
#pragma unroll
      for (int c = 0; c < 4; ++c) {
        bf16x8 b = *(const bf16x8*)&ldsB[(c * 4 + s) * 512 + lane * 8];
        acc[c] = __builtin_amdgcn_mfma_f32_16x16x32_bf16(a, b, acc[c], 0, 0, 0);
      }
    }
    // C/D: col = lane&15 (feat), row = q*4 + reg (node)
#pragma unroll
    for (int c = 0; c < 4; ++c)
#pragma unroll
      for (int r = 0; r < 4; ++r)
        H1b[(size_t)(node0 + q * 4 + r) * H_F + c * 16 + l] = f2bf(acc[c][r]);
  }
}

// ---------------- gather1f: slice sort + gather + FUSED gemm2 -------------
// Block = bin (128 nodes), 512 threads.
// Sort: bin's edges live as 196 per-block slices (ranges from offT). Pass 1
// streams dl bytes (hist, 2 threads/slice); scan; pass 2 scatters 4 B keys
// into LDS srt. Persist sorted keys + per-node segments for gather2s.
// Gather + fused gemm2: R8-proven bodies, unchanged.
__global__ __launch_bounds__(512) void gather1f_kernel(
    const uint2* __restrict__ H1q, const unsigned* __restrict__ rec4,
    const unsigned char* __restrict__ dl1, const int* __restrict__ offT,
    unsigned* __restrict__ srtG, int2* __restrict__ segB,
    const float* __restrict__ b1, const float* __restrict__ W2,
    unsigned short* __restrict__ H2b) {
  __shared__ int h[BIN_NODES], sc[BIN_NODES], cur[BIN_NODES];
  __shared__ int sS[196], sE[196];
  __shared__ unsigned srt[BCAP];
  __shared__ unsigned aggU[BIN_NODES * AGG_STRIDE];  // bf16-pair packed
  __shared__ short ldsW2[2 * 512];
  int b = blockIdx.x, tid = threadIdx.x;
  // W2 swizzle fill (before first barrier)
  for (int idx = tid; idx < 1024; idx += 512) {
    int sfrag = idx >> 9;
    int entry = idx & 511;
    int lane = entry >> 3, j = entry & 7;
    int k = sfrag * 32 + (lane >> 4) * 8 + j;
    int c = lane & 15;
    ldsW2[idx] = (short)f2bf(W2[k * C_F + c]);
  }
  if (tid < 196) {
    sS[tid] = offT[tid * 783 + b];
    sE[tid] = offT[tid * 783 + b + 1];
  }
  if (tid < BIN_NODES) h[tid] = 0;
  __syncthreads();
  // pass 1: histogram from dl bytes (2 threads per slice, interleaved)
  if (tid < 392) {
    int sl = tid >> 1, sub = tid & 1;
    for (int i = sS[sl] + sub; i < sE[sl]; i += 2) atomicAdd(&h[dl1[i]], 1);
  }
  __syncthreads();
  if (tid < BIN_NODES) sc[tid] = h[tid];
  __syncthreads();
#pragma unroll
  for (int d = 1; d < BIN_NODES; d <<= 1) {
    int t = 0;
    if (tid < BIN_NODES && tid >= d) t = sc[tid - d];
    __syncthreads();
    if (tid < BIN_NODES) sc[tid] += t;
    __syncthreads();
  }
  if (tid < BIN_NODES) cur[tid] = sc[tid] - h[tid];
  __syncthreads();
  // pass 2: scatter 4 B keys into sorted LDS
  if (tid < 392) {
    int sl = tid >> 1, sub = tid & 1;
    for (int i = sS[sl] + sub; i < sE[sl]; i += 2) {
      int dl = dl1[i];
      int pos = atomicAdd(&cur[dl], 1);
      srt[pos] = rec4[i];
    }
  }
  __syncthreads();
  // persist sorted keys (coalesced, bin-major) + per-node segments
  {
    int total = sc[BIN_NODES - 1];
    for (int i = tid; i < total; i += 512) srtG[(size_t)b * BCAP + i] = srt[i];
    if (tid < BIN_NODES) {
      int n = (b << BIN_SH) + tid;
      if (n < N_NODES) segB[n] = make_int2(sc[tid] - h[tid], sc[tid]);
    }
  }
  // ---- gather phase (R8 body) ----
  int wv = tid >> 6, lane = tid & 63, g = lane >> 4, li = lane & 15;
  const float wsc = 1.0f / 32767.0f;
  float bb0 = b1[li * 4], bb1 = b1[li * 4 + 1];
  float bb2 = b1[li * 4 + 2], bb3 = b1[li * 4 + 3];
  for (int k = 0; k < 16; ++k) {
    int nl = wv * 16 + k;
    int n = (b << BIN_SH) + nl;
    if (n >= N_NODES) break;
    int e1 = sc[nl], e0 = e1 - h[nl];
    f32x4 a0 = {0.f, 0.f, 0.f, 0.f}, a1 = {0.f, 0.f, 0.f, 0.f};
    f32x4 a2 = {0.f, 0.f, 0.f, 0.f}, a3 = {0.f, 0.f, 0.f, 0.f};
    int i = e0;
    for (; i + 15 < e1; i += 16) {
      unsigned r0 = srt[i + g];
      unsigned r1 = srt[i + 4 + g];
      unsigned r2 = srt[i + 8 + g];
      unsigned r3 = srt[i + 12 + g];
      uint2 v0 = H1q[(r0 & 0x1FFFF) * (H_F / 4) + li];
      uint2 v1 = H1q[(r1 & 0x1FFFF) * (H_F / 4) + li];
      uint2 v2 = H1q[(r2 & 0x1FFFF) * (H_F / 4) + li];
      uint2 v3 = H1q[(r3 & 0x1FFFF) * (H_F / 4) + li];
      float w0 = (float)(r0 >> 17) * wsc, w1 = (float)(r1 >> 17) * wsc;
      float w2 = (float)(r2 >> 17) * wsc, w3 = (float)(r3 >> 17) * wsc;
      a0[0] += __uint_as_float(v0.x << 16) * w0;
      a0[1] += __uint_as_float(v0.x & 0xFFFF0000u) * w0;
      a0[2] += __uint_as_float(v0.y << 16) * w0;
      a0[3] += __uint_as_float(v0.y & 0xFFFF0000u) * w0;
      a1[0] += __uint_as_float(v1.x << 16) * w1;
      a1[1] += __uint_as_float(v1.x & 0xFFFF0000u) * w1;
      a1[2] += __uint_as_float(v1.y << 16) * w1;
      a1[3] += __uint_as_float(v1.y & 0xFFFF0000u) * w1;
      a2[0] += __uint_as_float(v2.x << 16) * w2;
      a2[1] += __uint_as_float(v2.x & 0xFFFF0000u) * w2;
      a2[2] += __uint_as_float(v2.y << 16) * w2;
      a2[3] += __uint_as_float(v2.y & 0xFFFF0000u) * w2;
      a3[0] += __uint_as_float(v3.x << 16) * w3;
      a3[1] += __uint_as_float(v3.x & 0xFFFF0000u) * w3;
      a3[2] += __uint_as_float(v3.y << 16) * w3;
      a3[3] += __uint_as_float(v3.y & 0xFFFF0000u) * w3;
    }
    for (; i + 3 < e1; i += 4) {
      unsigned r0 = srt[i + g];
      uint2 v0 = H1q[(r0 & 0x1FFFF) * (H_F / 4) + li];
      float w0 = (float)(r0 >> 17) * wsc;
      a0[0] += __uint_as_float(v0.x << 16) * w0;
      a0[1] += __uint_as_float(v0.x & 0xFFFF0000u) * w0;
      a0[2] += __uint_as_float(v0.y << 16) * w0;
      a0[3] += __uint_as_float(v0.y & 0xFFFF0000u) * w0;
    }
    if (i + g < e1) {
      unsigned r0 = srt[i + g];
      uint2 v0 = H1q[(r0 & 0x1FFFF) * (H_F / 4) + li];
      float w0 = (float)(r0 >> 17) * wsc;
      a1[0] += __uint_as_float(v0.x << 16) * w0;
      a1[1] += __uint_as_float(v0.x & 0xFFFF0000u) * w0;
      a1[2] += __uint_as_float(v0.y << 16) * w0;
      a1[3] += __uint_as_float(v0.y & 0xFFFF0000u) * w0;
    }
    f32x4 a = (a0 + a1) + (a2 + a3);
#pragma unroll
    for (int c = 0; c < 4; ++c) {
      a[c] += __shfl_xor(a[c], 16, 64);
      a[c] += __shfl_xor(a[c], 32, 64);
    }
    if (g == 0) {
      float r0 = fmaxf(a[0] + bb0, 0.f);
      float r1 = fmaxf(a[1] + bb1, 0.f);
      float r2 = fmaxf(a[2] + bb2, 0.f);
      float r3 = fmaxf(a[3] + bb3, 0.f);
      unsigned p0 = (unsigned)f2bf(r0) | ((unsigned)f2bf(r1) << 16);
      unsigned p1 = (unsigned)f2bf(r2) | ((unsigned)f2bf(r3) << 16);
      *(uint2*)&aggU[nl * AGG_STRIDE + li * 2] = make_uint2(p0, p1);
    }
  }
  __syncthreads();
  // ---- fused gemm2 (R8 body) ----
  int l = lane & 15, q = lane >> 4;
  int nl0 = wv * 16;
  f32x4 acc = {0.f, 0.f, 0.f, 0.f};
#pragma unroll
  for (int s = 0; s < 2; ++s) {
    bf16x8 afr = *(const bf16x8*)&aggU[(nl0 + l) * AGG_STRIDE + s * 16 + q * 4];
    bf16x8 bfr = *(const bf16x8*)&ldsW2[s * 512 + lane * 8];
    acc = __builtin_amdgcn_mfma_f32_16x16x32_bf16(afr, bfr, acc, 0, 0, 0);
  }
  int node0 = (b << BIN_SH) + nl0;
#pragma unroll
  for (int r = 0; r < 4; ++r) {
    int n = node0 + q * 4 + r;
    if (n < N_NODES) H2b[(size_t)n * C_F + l] = f2bf(acc[r]);
  }
}

// ---------------- gather2s: NO sort — reuse gather1f's sorted keys --------
// (R8-proven structure; bin count now derived from segB of last bin node.)
__global__ __launch_bounds__(512) void gather2s_kernel(
    const uint2* __restrict__ H2q, const unsigned* __restrict__ srtG,
    const int2* __restrict__ segB, const float* __restrict__ b2,
    float* __restrict__ out) {
  __shared__ int2 segl[BIN_NODES];
  __shared__ unsigned srt[BCAP];
  __shared__ int scnt;
  int b = blockIdx.x, tid = threadIdx.x;
  if (tid < BIN_NODES) {
    int n = (b << BIN_SH) + tid;
    segl[tid] = (n < N_NODES) ? segB[n] : make_int2(0, 0);
  }
  if (tid == 0) {
    int lastv = (b << BIN_SH) + BIN_NODES - 1;
    if (lastv >= N_NODES) lastv = N_NODES - 1;
    scnt = segB[lastv].y;
  }
  __syncthreads();
  int cnt = scnt;
  for (int i = tid; i < cnt; i += 512) srt[i] = srtG[(size_t)b * BCAP + i];
  __syncthreads();
  // gather phase (R8 body)
  int wv = tid >> 6, lane = tid & 63, g = lane >> 2, li = lane & 3;
  const float wsc = 1.0f / 32767.0f;
  float bb0 = b2[li * 4], bb1 = b2[li * 4 + 1];
  float bb2 = b2[li * 4 + 2], bb3 = b2[li * 4 + 3];
  for (int k = 0; k < 16; ++k) {
    int nl = wv * 16 + k;
    int n = (b << BIN_SH) + nl;
    if (n >= N_NODES) break;
    int2 sgl = segl[nl];
    int e0 = sgl.x, e1 = sgl.y;
    f32x4 a0 = {0.f, 0.f, 0.f, 0.f};
    int i = e0;
    for (; i + 15 < e1; i += 16) {
      unsigned r0 = srt[i + g];
      uint2 v0 = H2q[(r0 & 0x1FFFF) * (C_F / 4) + li];
      float w0 = (float)(r0 >> 17) * wsc;
      a0[0] += __uint_as_float(v0.x << 16) * w0;
      a0[1] += __uint_as_float(v0.x & 0xFFFF0000u) * w0;
      a0[2] += __uint_as_float(v0.y << 16) * w0;
      a0[3] += __uint_as_float(v0.y & 0xFFFF0000u) * w0;
    }
    if (i + g < e1) {
      unsigned r0 = srt[i + g];
      uint2 v0 = H2q[(r0 & 0x1FFFF) * (C_F / 4) + li];
      float w0 = (float)(r0 >> 17) * wsc;
      a0[0] += __uint_as_float(v0.x << 16) * w0;
      a0[1] += __uint_as_float(v0.x & 0xFFFF0000u) * w0;
      a0[2] += __uint_as_float(v0.y << 16) * w0;
      a0[3] += __uint_as_float(v0.y & 0xFFFF0000u) * w0;
    }
#pragma unroll
    for (int c = 0; c < 4; ++c) {
      a0[c] += __shfl_xor(a0[c], 4, 64);
      a0[c] += __shfl_xor(a0[c], 8, 64);
      a0[c] += __shfl_xor(a0[c], 16, 64);
      a0[c] += __shfl_xor(a0[c], 32, 64);
    }
    if (g == 0) {
      float4 o;
      o.x = a0[0] + bb0;
      o.y = a0[1] + bb1;
      o.z = a0[2] + bb2;
      o.w = a0[3] + bb3;
      *(float4*)&out[(size_t)n * C_F + li * 4] = o;
    }
  }
}

extern "C" void kernel_launch(void* const* d_in, const int* in_sizes, int n_in,
                              void* d_out, int out_size, void* d_ws,
                              size_t ws_size, hipStream_t stream) {
  const float* X  = (const float*)d_in[0];
  const float* ew = (const float*)d_in[1];
  const float* W1 = (const float*)d_in[2];
  const float* b1 = (const float*)d_in[3];
  const float* W2 = (const float*)d_in[4];
  const float* b2 = (const float*)d_in[5];
  const int* src  = (const int*)d_in[6];
  const int* dst  = (const int*)d_in[7];
  float* out = (float*)d_out;

  // Workspace (~34.25 MB):
  //   H1b  bf16 [N x 64]            12.80 MB
  //   H2b  bf16 [N x 16]             3.20 MB
  //   rec4 uint [196 x 8192]         6.42 MB (src|wf<<17, block-region sorted)
  //   dl1  u8   [196 x 8192]         1.61 MB (dst lane per record)
  //   offT int  [196 x 783]          0.61 MB (per-block bin offsets + end)
  //   srtG uint [NBINS x BCAP]       8.81 MB (bin-major sorted keys, gather1f)
  //   segB int2 [N]                  0.80 MB (per-node {e0,e1} in bin)
  unsigned short* H1b = (unsigned short*)d_ws;
  unsigned short* H2b = H1b + (size_t)N_NODES * H_F;
  unsigned* rec4 = (unsigned*)(H2b + (size_t)N_NODES * C_F);
  unsigned char* dl1 = (unsigned char*)(rec4 + (size_t)PART_BLOCKS * PBE);
  int* offT = (int*)(dl1 + (size_t)PART_BLOCKS * PBE);
  unsigned* srtG = (unsigned*)(offT + PART_BLOCKS * 783);
  int2* segB = (int2*)(srtG + (size_t)NBINS * BCAP);

  part_gemm1_kernel<<<PART_BLOCKS + GEMM1_BLOCKS, 256, 0, stream>>>(
      src, dst, ew, rec4, dl1, offT, X, W1, H1b);
  gather1f_kernel<<<NBINS, 512, 0, stream>>>((const uint2*)H1b, rec4, dl1,
                                             offT, srtG, segB, b1, W2, H2b);
  gather2s_kernel<<<NBINS, 512, 0, stream>>>((const uint2*)H2b, srtG, segB, b2,
                                             out);
}

// Round 10
// 217.524 us; speedup vs baseline: 1.0009x; 1.0009x over previous
//
#include <hip/hip_runtime.h>

#define N_NODES 100000
#define N_EDGES 1600000
#define IN_F 128
#define H_F 64
#define C_F 16

#define BIN_SH 7
#define BIN_NODES 128          // 1 << BIN_SH
#define NBINS 782              // ceil(100000 / 128)
#define BCAP 2816              // fixed bin capacity (mean 2048, sigma 45 -> +17s)
#define PART_BLOCKS 196        // ceil(400000 int4 / 2048 per block) - 8192 edges/blk
#define GEMM1_BLOCKS 1563      // ceil(6250 row-tiles / 4 waves)
#define RMAX 6                 // ceil(BCAP / 512) records/thread in sort cache
#define AGG_STRIDE 36          // LDS agg tile row stride in words (144 B)

typedef __attribute__((ext_vector_type(8))) short bf16x8;  // 8 bf16 (4 VGPRs)
typedef __attribute__((ext_vector_type(4))) float f32x4;   // MFMA C/D

// fp32 -> bf16 round-to-nearest-even (finite inputs)
__device__ inline unsigned short f2bf(float f) {
  unsigned u = __float_as_uint(f);
  unsigned r = (u + 0x7fff + ((u >> 16) & 1)) >> 16;
  return (unsigned short)r;
}

// ---------------- fused partition + GEMM1 (R8-proven, 202 us wall) --------
// Blocks [0, PART_BLOCKS): partition edges into 782 shared fixed-capacity
// bins, 8192 edges/block (32/thread) -> long per-(block,bin) runs minimize
// cross-XCD partial-line writeback (R4/R8 measured).
// Blocks [PART_BLOCKS..): MFMA GEMM1 H1b = bf16(X @ W1).
__global__ __launch_bounds__(256) void part_gemm1_kernel(
    const int* __restrict__ src, const int* __restrict__ dst,
    const float* __restrict__ ew, int* __restrict__ binCnt,
    int2* __restrict__ ebin, const float* __restrict__ X,
    const float* __restrict__ W1, unsigned short* __restrict__ H1b) {
  __shared__ char ldsraw[16 * 1024];
  int tid = threadIdx.x;
  if (blockIdx.x < PART_BLOCKS) {
    // ---- partition path ----
    int* hist = (int*)ldsraw;   // NBINS ints
    int* base = hist + NBINS;   // NBINS ints (reserve base, then cursor)
    for (int i = tid; i < NBINS; i += 256) hist[i] = 0;
    __syncthreads();
    int i0 = blockIdx.x * 2048;  // int4 index base (8192 edges/block)
    int iHi = i0 + 2048;
    if (iHi > N_EDGES / 4) iHi = N_EDGES / 4;
    const int4* d4p = (const int4*)dst;
    const int4* s4p = (const int4*)src;
    const float4* w4p = (const float4*)ew;
    unsigned key[32];
    unsigned aux[32];
#pragma unroll
    for (int it = 0; it < 8; ++it) {
      int i = i0 + it * 256 + tid;
      if (i < iHi) {
        int4 d = d4p[i];
        int4 s = s4p[i];
        float4 w = w4p[i];
#pragma unroll
        for (int j = 0; j < 4; ++j) {
          int dd = (&d.x)[j];
          int ss = (&s.x)[j];
          float ww = (&w.x)[j];
          int bb = dd >> BIN_SH;
          unsigned wf = (unsigned)(ww * 32767.0f + 0.5f);
          key[it * 4 + j] =
              (unsigned)ss | ((unsigned)(dd & (BIN_NODES - 1)) << 17);
          aux[it * 4 + j] = wf | ((unsigned)bb << 15);
          atomicAdd(&hist[bb], 1);
        }
      }
    }
    __syncthreads();
    for (int i = tid; i < NBINS; i += 256)
      base[i] = hist[i] ? atomicAdd(&binCnt[i], hist[i]) : 0;
    __syncthreads();
#pragma unroll
    for (int it = 0; it < 8; ++it) {
      int i = i0 + it * 256 + tid;
      if (i < iHi) {
        int pos[4];
#pragma unroll
        for (int j = 0; j < 4; ++j)
          pos[j] = atomicAdd(&base[aux[it * 4 + j] >> 15], 1);
#pragma unroll
        for (int j = 0; j < 4; ++j) {
          unsigned a = aux[it * 4 + j];
          ebin[(size_t)(a >> 15) * BCAP + pos[j]] =
              make_int2((int)key[it * 4 + j], (int)(a & 0x7FFF));
        }
      }
    }
  } else {
    // ---- gemm1 path ----
    short* ldsB = (short*)ldsraw;  // 16 frags x 512 bf16 = 16 KB
    for (int idx = tid; idx < 16 * 512; idx += 256) {
      int frag = idx >> 9;    // c*4 + s
      int entry = idx & 511;  // lane*8 + j
      int lane = entry >> 3, j = entry & 7;
      int c = frag >> 2, s = frag & 3;
      int k = s * 32 + (lane >> 4) * 8 + j;
      int n = c * 16 + (lane & 15);
      ldsB[idx] = (short)f2bf(W1[k * H_F + n]);
    }
    __syncthreads();
    int wave = tid >> 6;
    int lane = tid & 63;
    int rt = (blockIdx.x - PART_BLOCKS) * 4 + wave;  // 16-node row tile
    if (rt >= N_NODES / 16) return;                  // 6250 tiles exactly
    int node0 = rt * 16;
    int l = lane & 15, q = lane >> 4;
    const float* xp = X + (size_t)(node0 + l) * IN_F + q * 8;
    f32x4 acc[4] = {f32x4{0.f, 0.f, 0.f, 0.f}, f32x4{0.f, 0.f, 0.f, 0.f},
                    f32x4{0.f, 0.f, 0.f, 0.f}, f32x4{0.f, 0.f, 0.f, 0.f}};
#pragma unroll
    for (int s = 0; s < 4; ++s) {
      float4 x0 = *(const float4*)(xp + s * 32);
      float4 x1 = *(const float4*)(xp + s * 32 + 4);
      bf16x8 a;
      a[0] = f2bf(x0.x); a[1] = f2bf(x0.y); a[2] = f2bf(x0.z); a[3] = f2bf(x0.w);
      a[4] = f2bf(x1.x); a[5] = f2bf(x1.y); a[6] = f2bf(x1.z); a[7] = f2bf(x1.w);
#pragma unroll
      for (int c = 0; c < 4; ++c) {
        bf16x8 b = *(const bf16x8*)&ldsB[(c * 4 + s) * 512 + lane * 8];
        acc[c] = __builtin_amdgcn_mfma_f32_16x16x32_bf16(a, b, acc[c], 0, 0, 0);
      }
    }
    // C/D: col = lane&15 (feat), row = q*4 + reg (node)
#pragma unroll
    for (int c = 0; c < 4; ++c)
#pragma unroll
      for (int r = 0; r < 4; ++r)
        H1b[(size_t)(node0 + q * 4 + r) * H_F + c * 16 + l] = f2bf(acc[c][r]);
  }
}

// ---------------- gather1f: per-bin sort + PAIRED gather + fused gemm2 ----
// Block = bin (128 nodes), 512 threads. Sort/persist = R8-proven.
// Gather NEW: each wave processes node pairs (k, k+8) concurrently — both
// nodes' srt reads + H1q loads issue before either consumes (wave-uniform
// branches; partial vmcnt keeps the second node's loads in flight) ->
// 2x memory-level parallelism, zero extra arithmetic.
__global__ __launch_bounds__(512) void gather1f_kernel(
    const uint2* __restrict__ H1q, const int* __restrict__ binCnt,
    int2* __restrict__ ebin, int2* __restrict__ segB,
    const float* __restrict__ b1, const float* __restrict__ W2,
    unsigned short* __restrict__ H2b) {
  __shared__ int h[BIN_NODES], sc[BIN_NODES], cur[BIN_NODES];
  __shared__ unsigned srt[BCAP];
  __shared__ unsigned aggU[BIN_NODES * AGG_STRIDE];  // bf16-pair packed
  __shared__ short ldsW2[2 * 512];
  int b = blockIdx.x, tid = threadIdx.x;
  // W2 swizzle fill (overlaps sort; before first barrier)
  for (int idx = tid; idx < 1024; idx += 512) {
    int sfrag = idx >> 9;
    int entry = idx & 511;
    int lane = entry >> 3, j = entry & 7;
    int k = sfrag * 32 + (lane >> 4) * 8 + j;
    int c = lane & 15;
    ldsW2[idx] = (short)f2bf(W2[k * C_F + c]);
  }
  int lo = b * BCAP;
  int cnt = binCnt[b];
  if (tid < BIN_NODES) h[tid] = 0;
  __syncthreads();
  unsigned rk[RMAX];
  int rd[RMAX];
  int rn = 0;
#pragma unroll
  for (int j = 0; j < RMAX; ++j) {
    int e = j * 512 + tid;
    if (e < cnt) {
      int2 r = ebin[lo + e];
      int dl = (((unsigned)r.x) >> 17) & (BIN_NODES - 1);
      rk[j] = ((unsigned)r.x & 0x1FFFF) | ((unsigned)r.y << 17);
      rd[j] = dl;
      atomicAdd(&h[dl], 1);
      rn = j + 1;
    }
  }
  __syncthreads();
  if (tid < BIN_NODES) sc[tid] = h[tid];
  __syncthreads();
#pragma unroll
  for (int d = 1; d < BIN_NODES; d <<= 1) {
    int t = 0;
    if (tid < BIN_NODES && tid >= d) t = sc[tid - d];
    __syncthreads();
    if (tid < BIN_NODES) sc[tid] += t;
    __syncthreads();
  }
  if (tid < BIN_NODES) cur[tid] = sc[tid] - h[tid];
  __syncthreads();
#pragma unroll
  for (int j = 0; j < RMAX; ++j)
    if (j < rn) {
      int pos = atomicAdd(&cur[rd[j]], 1);
      srt[pos] = rk[j];
    }
  __syncthreads();
  // ---- persist sorted keys + per-node bin-local segments for gather2s ----
  {
    unsigned* ebinU = (unsigned*)ebin;
    int lo2 = lo << 1;  // 4 B-unit base of this bin's 8 B region
    for (int i = tid; i < cnt; i += 512) ebinU[lo2 + i] = srt[i];
    if (tid < BIN_NODES) {
      int n = (b << BIN_SH) + tid;
      if (n < N_NODES) segB[n] = make_int2(sc[tid] - h[tid], sc[tid]);
    }
  }
  // ---- gather phase: paired nodes (k, k+8) ----
  int wv = tid >> 6, lane = tid & 63, g = lane >> 4, li = lane & 15;
  const float wsc = 1.0f / 32767.0f;
  float bb0 = b1[li * 4], bb1 = b1[li * 4 + 1];
  float bb2 = b1[li * 4 + 2], bb3 = b1[li * 4 + 3];
  int nbase = b << BIN_SH;
  for (int k = 0; k < 8; ++k) {
    int nlA = wv * 16 + k;
    int nlB = nlA + 8;
    int eA1 = sc[nlA], eA0 = eA1 - h[nlA];
    int eB1 = sc[nlB], eB0 = eB1 - h[nlB];
    f32x4 aA0 = {0.f, 0.f, 0.f, 0.f}, aA1 = {0.f, 0.f, 0.f, 0.f};
    f32x4 aB0 = {0.f, 0.f, 0.f, 0.f}, aB1 = {0.f, 0.f, 0.f, 0.f};
    int iA = eA0, iB = eB0;
    bool mA = iA + 15 < eA1, mB = iB + 15 < eB1;
    while (mA || mB) {  // wave-uniform
      unsigned rA0, rA1, rA2, rA3, rB0, rB1, rB2, rB3;
      uint2 vA0, vA1, vA2, vA3, vB0, vB1, vB2, vB3;
      if (mA) {
        rA0 = srt[iA + g];
        rA1 = srt[iA + 4 + g];
        rA2 = srt[iA + 8 + g];
        rA3 = srt[iA + 12 + g];
        vA0 = H1q[(rA0 & 0x1FFFF) * (H_F / 4) + li];
        vA1 = H1q[(rA1 & 0x1FFFF) * (H_F / 4) + li];
        vA2 = H1q[(rA2 & 0x1FFFF) * (H_F / 4) + li];
        vA3 = H1q[(rA3 & 0x1FFFF) * (H_F / 4) + li];
      }
      if (mB) {
        rB0 = srt[iB + g];
        rB1 = srt[iB + 4 + g];
        rB2 = srt[iB + 8 + g];
        rB3 = srt[iB + 12 + g];
        vB0 = H1q[(rB0 & 0x1FFFF) * (H_F / 4) + li];
        vB1 = H1q[(rB1 & 0x1FFFF) * (H_F / 4) + li];
        vB2 = H1q[(rB2 & 0x1FFFF) * (H_F / 4) + li];
        vB3 = H1q[(rB3 & 0x1FFFF) * (H_F / 4) + li];
      }
      if (mA) {
        float w0 = (float)(rA0 >> 17) * wsc, w1 = (float)(rA1 >> 17) * wsc;
        float w2 = (float)(rA2 >> 17) * wsc, w3 = (float)(rA3 >> 17) * wsc;
        aA0[0] += __uint_as_float(vA0.x << 16) * w0;
        aA0[1] += __uint_as_float(vA0.x & 0xFFFF0000u) * w0;
        aA0[2] += __uint_as_float(vA0.y << 16) * w0;
        aA0[3] += __uint_as_float(vA0.y & 0xFFFF0000u) * w0;
        aA1[0] += __uint_as_float(vA1.x << 16) * w1;
        aA1[1] += __uint_as_float(vA1.x & 0xFFFF0000u) * w1;
        aA1[2] += __uint_as_float(vA1.y << 16) * w1;
        aA1[3] += __uint_as_float(vA1.y & 0xFFFF0000u) * w1;
        aA0[0] += __uint_as_float(vA2.x << 16) * w2;
        aA0[1] += __uint_as_float(vA2.x & 0xFFFF0000u) * w2;
        aA0[2] += __uint_as_float(vA2.y << 16) * w2;
        aA0[3] += __uint_as_float(vA2.y & 0xFFFF0000u) * w2;
        aA1[0] += __uint_as_float(vA3.x << 16) * w3;
        aA1[1] += __uint_as_float(vA3.x & 0xFFFF0000u) * w3;
        aA1[2] += __uint_as_float(vA3.y << 16) * w3;
        aA1[3] += __uint_as_float(vA3.y & 0xFFFF0000u) * w3;
        iA += 16;
      }
      if (mB) {
        float w0 = (float)(rB0 >> 17) * wsc, w1 = (float)(rB1 >> 17) * wsc;
        float w2 = (float)(rB2 >> 17) * wsc, w3 = (float)(rB3 >> 17) * wsc;
        aB0[0] += __uint_as_float(vB0.x << 16) * w0;
        aB0[1] += __uint_as_float(vB0.x & 0xFFFF0000u) * w0;
        aB0[2] += __uint_as_float(vB0.y << 16) * w0;
        aB0[3] += __uint_as_float(vB0.y & 0xFFFF0000u) * w0;
        aB1[0] += __uint_as_float(vB1.x << 16) * w1;
        aB1[1] += __uint_as_float(vB1.x & 0xFFFF0000u) * w1;
        aB1[2] += __uint_as_float(vB1.y << 16) * w1;
        aB1[3] += __uint_as_float(vB1.y & 0xFFFF0000u) * w1;
        aB0[0] += __uint_as_float(vB2.x << 16) * w2;
        aB0[1] += __uint_as_float(vB2.x & 0xFFFF0000u) * w2;
        aB0[2] += __uint_as_float(vB2.y << 16) * w2;
        aB0[3] += __uint_as_float(vB2.y & 0xFFFF0000u) * w2;
        aB1[0] += __uint_as_float(vB3.x << 16) * w3;
        aB1[1] += __uint_as_float(vB3.x & 0xFFFF0000u) * w3;
        aB1[2] += __uint_as_float(vB3.y << 16) * w3;
        aB1[3] += __uint_as_float(vB3.y & 0xFFFF0000u) * w3;
        iB += 16;
      }
      mA = iA + 15 < eA1;
      mB = iB + 15 < eB1;
    }
    // paired 4-wide tails (wave-uniform)
    bool tA = iA + 3 < eA1, tB = iB + 3 < eB1;
    while (tA || tB) {
      unsigned rA0, rB0;
      uint2 vA0, vB0;
      if (tA) {
        rA0 = srt[iA + g];
        vA0 = H1q[(rA0 & 0x1FFFF) * (H_F / 4) + li];
      }
      if (tB) {
        rB0 = srt[iB + g];
        vB0 = H1q[(rB0 & 0x1FFFF) * (H_F / 4) + li];
      }
      if (tA) {
        float w0 = (float)(rA0 >> 17) * wsc;
        aA0[0] += __uint_as_float(vA0.x << 16) * w0;
        aA0[1] += __uint_as_float(vA0.x & 0xFFFF0000u) * w0;
        aA0[2] += __uint_as_float(vA0.y << 16) * w0;
        aA0[3] += __uint_as_float(vA0.y & 0xFFFF0000u) * w0;
        iA += 4;
      }
      if (tB) {
        float w0 = (float)(rB0 >> 17) * wsc;
        aB0[0] += __uint_as_float(vB0.x << 16) * w0;
        aB0[1] += __uint_as_float(vB0.x & 0xFFFF0000u) * w0;
        aB0[2] += __uint_as_float(vB0.y << 16) * w0;
        aB0[3] += __uint_as_float(vB0.y & 0xFFFF0000u) * w0;
        iB += 4;
      }
      tA = iA + 3 < eA1;
      tB = iB + 3 < eB1;
    }
    // finals (<=3 edges each; per-lane predicated)
    {
      bool fA = iA + g < eA1, fB = iB + g < eB1;
      unsigned rA0 = 0, rB0 = 0;
      uint2 vA0, vB0;
      if (fA) {
        rA0 = srt[iA + g];
        vA0 = H1q[(rA0 & 0x1FFFF) * (H_F / 4) + li];
      }
      if (fB) {
        rB0 = srt[iB + g];
        vB0 = H1q[(rB0 & 0x1FFFF) * (H_F / 4) + li];
      }
      if (fA) {
        float w0 = (float)(rA0 >> 17) * wsc;
        aA1[0] += __uint_as_float(vA0.x << 16) * w0;
        aA1[1] += __uint_as_float(vA0.x & 0xFFFF0000u) * w0;
        aA1[2] += __uint_as_float(vA0.y << 16) * w0;
        aA1[3] += __uint_as_float(vA0.y & 0xFFFF0000u) * w0;
      }
      if (fB) {
        float w0 = (float)(rB0 >> 17) * wsc;
        aB1[0] += __uint_as_float(vB0.x << 16) * w0;
        aB1[1] += __uint_as_float(vB0.x & 0xFFFF0000u) * w0;
        aB1[2] += __uint_as_float(vB0.y << 16) * w0;
        aB1[3] += __uint_as_float(vB0.y & 0xFFFF0000u) * w0;
      }
    }
    // reduce + epilogue, node A then node B
    f32x4 a = aA0 + aA1;
#pragma unroll
    for (int c = 0; c < 4; ++c) {
      a[c] += __shfl_xor(a[c], 16, 64);
      a[c] += __shfl_xor(a[c], 32, 64);
    }
    if (g == 0 && nbase + nlA < N_NODES) {
      float r0 = fmaxf(a[0] + bb0, 0.f);
      float r1 = fmaxf(a[1] + bb1, 0.f);
      float r2 = fmaxf(a[2] + bb2, 0.f);
      float r3 = fmaxf(a[3] + bb3, 0.f);
      unsigned p0 = (unsigned)f2bf(r0) | ((unsigned)f2bf(r1) << 16);
      unsigned p1 = (unsigned)f2bf(r2) | ((unsigned)f2bf(r3) << 16);
      *(uint2*)&aggU[nlA * AGG_STRIDE + li * 2] = make_uint2(p0, p1);
    }
    f32x4 bs = aB0 + aB1;
#pragma unroll
    for (int c = 0; c < 4; ++c) {
      bs[c] += __shfl_xor(bs[c], 16, 64);
      bs[c] += __shfl_xor(bs[c], 32, 64);
    }
    if (g == 0 && nbase + nlB < N_NODES) {
      float r0 = fmaxf(bs[0] + bb0, 0.f);
      float r1 = fmaxf(bs[1] + bb1, 0.f);
      float r2 = fmaxf(bs[2] + bb2, 0.f);
      float r3 = fmaxf(bs[3] + bb3, 0.f);
      unsigned p0 = (unsigned)f2bf(r0) | ((unsigned)f2bf(r1) << 16);
      unsigned p1 = (unsigned)f2bf(r2) | ((unsigned)f2bf(r3) << 16);
      *(uint2*)&aggU[nlB * AGG_STRIDE + li * 2] = make_uint2(p0, p1);
    }
  }
  __syncthreads();
  // ---- fused gemm2: wave wv handles nodes wv*16..wv*16+15 ----
  int l = lane & 15, q = lane >> 4;
  int nl0 = wv * 16;
  f32x4 acc = {0.f, 0.f, 0.f, 0.f};
#pragma unroll
  for (int s = 0; s < 2; ++s) {
    bf16x8 afr = *(const bf16x8*)&aggU[(nl0 + l) * AGG_STRIDE + s * 16 + q * 4];
    bf16x8 bfr = *(const bf16x8*)&ldsW2[s * 512 + lane * 8];
    acc = __builtin_amdgcn_mfma_f32_16x16x32_bf16(afr, bfr, acc, 0, 0, 0);
  }
  int node0 = (b << BIN_SH) + nl0;
#pragma unroll
  for (int r = 0; r < 4; ++r) {
    int n = node0 + q * 4 + r;
    if (n < N_NODES) H2b[(size_t)n * C_F + l] = f2bf(acc[r]);
  }
}

// ---------------- gather2s: NO sort + PAIRED gather -----------------------
// R8 load/sort-free structure; gather pairs nodes (k, k+8) for 2x MLP.
__global__ __launch_bounds__(512) void gather2s_kernel(
    const uint2* __restrict__ H2q, const int* __restrict__ binCnt,
    const int2* __restrict__ ebin, const int2* __restrict__ segB,
    const float* __restrict__ b2, float* __restrict__ out) {
  __shared__ int2 segl[BIN_NODES];
  __shared__ unsigned srt[BCAP];
  int b = blockIdx.x, tid = threadIdx.x;
  int cnt = binCnt[b];
  const unsigned* ebinU = (const unsigned*)ebin;
  int lo2 = (b * BCAP) << 1;
  for (int i = tid; i < cnt; i += 512) srt[i] = ebinU[lo2 + i];
  if (tid < BIN_NODES) {
    int n = (b << BIN_SH) + tid;
    segl[tid] = (n < N_NODES) ? segB[n] : make_int2(0, 0);
  }
  __syncthreads();
  // gather phase: paired nodes (k, k+8)
  int wv = tid >> 6, lane = tid & 63, g = lane >> 2, li = lane & 3;
  const float wsc = 1.0f / 32767.0f;
  float bb0 = b2[li * 4], bb1 = b2[li * 4 + 1];
  float bb2 = b2[li * 4 + 2], bb3 = b2[li * 4 + 3];
  int nbase = b << BIN_SH;
  for (int k = 0; k < 8; ++k) {
    int nlA = wv * 16 + k;
    int nlB = nlA + 8;
    int2 sA = segl[nlA];
    int2 sB = segl[nlB];
    int iA = sA.x, eA1 = sA.y;
    int iB = sB.x, eB1 = sB.y;
    f32x4 aA = {0.f, 0.f, 0.f, 0.f}, aB = {0.f, 0.f, 0.f, 0.f};
    bool mA = iA + 15 < eA1, mB = iB + 15 < eB1;
    while (mA || mB) {  // wave-uniform
      unsigned rA0, rB0;
      uint2 vA0, vB0;
      if (mA) {
        rA0 = srt[iA + g];
        vA0 = H2q[(rA0 & 0x1FFFF) * (C_F / 4) + li];
      }
      if (mB) {
        rB0 = srt[iB + g];
        vB0 = H2q[(rB0 & 0x1FFFF) * (C_F / 4) + li];
      }
      if (mA) {
        float w0 = (float)(rA0 >> 17) * wsc;
        aA[0] += __uint_as_float(vA0.x << 16) * w0;
        aA[1] += __uint_as_float(vA0.x & 0xFFFF0000u) * w0;
        aA[2] += __uint_as_float(vA0.y << 16) * w0;
        aA[3] += __uint_as_float(vA0.y & 0xFFFF0000u) * w0;
        iA += 16;
      }
      if (mB) {
        float w0 = (float)(rB0 >> 17) * wsc;
        aB[0] += __uint_as_float(vB0.x << 16) * w0;
        aB[1] += __uint_as_float(vB0.x & 0xFFFF0000u) * w0;
        aB[2] += __uint_as_float(vB0.y << 16) * w0;
        aB[3] += __uint_as_float(vB0.y & 0xFFFF0000u) * w0;
        iB += 16;
      }
      mA = iA + 15 < eA1;
      mB = iB + 15 < eB1;
    }
    // finals (per-lane predicated)
    {
      bool fA = iA + g < eA1, fB = iB + g < eB1;
      unsigned rA0 = 0, rB0 = 0;
      uint2 vA0, vB0;
      if (fA) {
        rA0 = srt[iA + g];
        vA0 = H2q[(rA0 & 0x1FFFF) * (C_F / 4) + li];
      }
      if (fB) {
        rB0 = srt[iB + g];
        vB0 = H2q[(rB0 & 0x1FFFF) * (C_F / 4) + li];
      }
      if (fA) {
        float w0 = (float)(rA0 >> 17) * wsc;
        aA[0] += __uint_as_float(vA0.x << 16) * w0;
        aA[1] += __uint_as_float(vA0.x & 0xFFFF0000u) * w0;
        aA[2] += __uint_as_float(vA0.y << 16) * w0;
        aA[3] += __uint_as_float(vA0.y & 0xFFFF0000u) * w0;
      }
      if (fB) {
        float w0 = (float)(rB0 >> 17) * wsc;
        aB[0] += __uint_as_float(vB0.x << 16) * w0;
        aB[1] += __uint_as_float(vB0.x & 0xFFFF0000u) * w0;
        aB[2] += __uint_as_float(vB0.y << 16) * w0;
        aB[3] += __uint_as_float(vB0.y & 0xFFFF0000u) * w0;
      }
    }
#pragma unroll
    for (int c = 0; c < 4; ++c) {
      aA[c] += __shfl_xor(aA[c], 4, 64);
      aA[c] += __shfl_xor(aA[c], 8, 64);
      aA[c] += __shfl_xor(aA[c], 16, 64);
      aA[c] += __shfl_xor(aA[c], 32, 64);
    }
    if (g == 0 && nbase + nlA < N_NODES) {
      float4 o;
      o.x = aA[0] + bb0;
      o.y = aA[1] + bb1;
      o.z = aA[2] + bb2;
      o.w = aA[3] + bb3;
      *(float4*)&out[(size_t)(nbase + nlA) * C_F + li * 4] = o;
    }
#pragma unroll
    for (int c = 0; c < 4; ++c) {
      aB[c] += __shfl_xor(aB[c], 4, 64);
      aB[c] += __shfl_xor(aB[c], 8, 64);
      aB[c] += __shfl_xor(aB[c], 16, 64);
      aB[c] += __shfl_xor(aB[c], 32, 64);
    }
    if (g == 0 && nbase + nlB < N_NODES) {
      float4 o;
      o.x = aB[0] + bb0;
      o.y = aB[1] + bb1;
      o.z = aB[2] + bb2;
      o.w = aB[3] + bb3;
      *(float4*)&out[(size_t)(nbase + nlB) * C_F + li * 4] = o;
    }
  }
}

extern "C" void kernel_launch(void* const* d_in, const int* in_sizes, int n_in,
                              void* d_out, int out_size, void* d_ws,
                              size_t ws_size, hipStream_t stream) {
  const float* X  = (const float*)d_in[0];
  const float* ew = (const float*)d_in[1];
  const float* W1 = (const float*)d_in[2];
  const float* b1 = (const float*)d_in[3];
  const float* W2 = (const float*)d_in[4];
  const float* b2 = (const float*)d_in[5];
  const int* src  = (const int*)d_in[6];
  const int* dst  = (const int*)d_in[7];
  float* out = (float*)d_out;

  // Workspace (~34.4 MB):
  //   H1b bf16 [N x 64] 12.8 MB
  //   H2b bf16 [N x 16]  3.2 MB (separate: live while H1b is read)
  //   ebin int2 [NBINS x BCAP] 17.6 MB (bins; reused for sorted 4 B keys)
  //   binCnt int [NBINS]
  //   segB int2 [N] 0.8 MB (per-node bin-local {e0,e1}, written by gather1f)
  unsigned short* H1b = (unsigned short*)d_ws;
  unsigned short* H2b = H1b + (size_t)N_NODES * H_F;
  int2* ebin  = (int2*)(H2b + (size_t)N_NODES * C_F);
  int* binCnt = (int*)(ebin + (size_t)NBINS * BCAP);
  int2* segB  = (int2*)(binCnt + NBINS);

  hipMemsetAsync(binCnt, 0, NBINS * sizeof(int), stream);
  part_gemm1_kernel<<<PART_BLOCKS + GEMM1_BLOCKS, 256, 0, stream>>>(
      src, dst, ew, binCnt, ebin, X, W1, H1b);
  gather1f_kernel<<<NBINS, 512, 0, stream>>>((const uint2*)H1b, binCnt, ebin,
                                             segB, b1, W2, H2b);
  gather2s_kernel<<<NBINS, 512, 0, stream>>>((const uint2*)H2b, binCnt, ebin,
                                             segB, b2, out);
}